// Round 4
// baseline (140.617 us; speedup 1.0000x reference)
//
#include <hip/hip_runtime.h>
#include <hip/hip_bf16.h>

typedef __bf16 bf16_t;
typedef __bf16 bf16x8 __attribute__((ext_vector_type(8)));
typedef float  f32x4  __attribute__((ext_vector_type(4)));

#define MFMA16(a, b, c) __builtin_amdgcn_mfma_f32_16x16x32_bf16((a), (b), (c), 0, 0, 0)

constexpr int Bc = 4, Lc = 2048, Hc = 8, Dc = 64;
constexpr int HD = Hc * Dc;            // 512
constexpr int TRAINc = 1536;
constexpr int ROWS_BLK = 128;          // q rows per workgroup (8 waves x 16)
constexpr int KT = 128;                // keys per k-tile (doubled: halves the serial chain)

constexpr int PREPK_BLOCKS = (int)((size_t)Bc * Lc * Hc * Dc / 8 / 256);  // 2048

// ---------------- fused prep: K cast + V transpose in one launch ----------------
__global__ void prep_fused(const float* __restrict__ K, bf16_t* __restrict__ Kb,
                           const float* __restrict__ V, bf16_t* __restrict__ Vt) {
  // [64][64] tile; 8-elem (16B) chunk c of row r stored at chunk c ^ (r>>3):
  // column reads then spread 64 lanes over all 32 banks (2/bank = free).
  __shared__ bf16_t T[64][64];
  const int t = (int)threadIdx.x;

  if ((int)blockIdx.x < PREPK_BLOCKS) {
    size_t g = ((size_t)blockIdx.x * 256 + t) * 8;
    float4 a = *(const float4*)(K + g);
    float4 b = *(const float4*)(K + g + 4);
    bf16x8 v;
    v[0] = (bf16_t)a.x; v[1] = (bf16_t)a.y; v[2] = (bf16_t)a.z; v[3] = (bf16_t)a.w;
    v[4] = (bf16_t)b.x; v[5] = (bf16_t)b.y; v[6] = (bf16_t)b.z; v[7] = (bf16_t)b.w;
    *(bf16x8*)(Kb + g) = v;
    return;
  }

  const int bid = (int)blockIdx.x - PREPK_BLOCKS;
  const int kt = bid & 31, h = (bid >> 5) & 7, b = bid >> 8;
  {
    int kl = t >> 2, dp = (t & 3) << 4;
    const float* s = V + ((size_t)(b * Lc + kt * 64 + kl) * Hc + h) * Dc + dp;
    bf16x8 v0, v1;
    float4 f;
    f = *(const float4*)(s);      v0[0]=(bf16_t)f.x; v0[1]=(bf16_t)f.y; v0[2]=(bf16_t)f.z; v0[3]=(bf16_t)f.w;
    f = *(const float4*)(s + 4);  v0[4]=(bf16_t)f.x; v0[5]=(bf16_t)f.y; v0[6]=(bf16_t)f.z; v0[7]=(bf16_t)f.w;
    f = *(const float4*)(s + 8);  v1[0]=(bf16_t)f.x; v1[1]=(bf16_t)f.y; v1[2]=(bf16_t)f.z; v1[3]=(bf16_t)f.w;
    f = *(const float4*)(s + 12); v1[4]=(bf16_t)f.x; v1[5]=(bf16_t)f.y; v1[6]=(bf16_t)f.z; v1[7]=(bf16_t)f.w;
    const int x = kl >> 3;
    const int c0 = dp >> 3;
    *(bf16x8*)&T[kl][(c0 ^ x) << 3]       = v0;
    *(bf16x8*)&T[kl][((c0 + 1) ^ x) << 3] = v1;
  }
  __syncthreads();
  {
    int d = t >> 2, kp = (t & 3) << 4;
    const int xa = kp >> 3;
    const int xb = xa + 1;
    const int lo = d & 7, hi = d >> 3;
    const int x0 = ((hi ^ xa) << 3) + lo;
    const int x1 = ((hi ^ xb) << 3) + lo;
    bf16x8 o0, o1;
#pragma unroll
    for (int i = 0; i < 8; ++i) { o0[i] = T[kp + i][x0]; o1[i] = T[kp + 8 + i][x1]; }
    bf16_t* dst = Vt + ((size_t)((b * Hc + h) * Dc + d)) * Lc + kt * 64 + kp;
    *(bf16x8*)dst = o0;
    *(bf16x8*)(dst + 8) = o1;
  }
}

// ---------------- main attention ----------------
static __device__ __forceinline__ void load16(const bf16_t* g, bf16_t* l) {
  __builtin_amdgcn_global_load_lds(
      (const __attribute__((address_space(1))) unsigned int*)g,
      (__attribute__((address_space(3))) unsigned int*)l, 16, 0, 0);
}

// 8 waves x 16 q-rows; KT=128 keys per phase -> longest serial chain 26 -> 13 phases.
// LDS: K 2x16K + V 2x16K + P 8x2K = 80 KB -> 2 blocks/CU.
__global__ __launch_bounds__(512, 4)
void continual_attn(const float* __restrict__ Qg, const bf16_t* __restrict__ Kb,
                    const bf16_t* __restrict__ Vt, const int* __restrict__ ATT,
                    float* __restrict__ OUT)
{
  // K rows: [key][64 d] = 128B rows, 16B slot s of row r holds logical chunk s^(r&7).
  // V rows: [d][128 key] = 256B rows; swizzle applied independently per 128B half.
  __shared__ __align__(16) bf16_t Klds[2][KT * 64];   // 2 x 16 KB
  __shared__ __align__(16) bf16_t Vlds[2][Dc * KT];   // 2 x 16 KB
  __shared__ __align__(16) bf16_t Plds[8][16 * 64];   // 16 KB (64-key buffer, reused per half)

  const int bid  = blockIdx.x;
  // complementary pairing: first 256 blocks get qblk 15..8 (heavy), second 256
  // get 0..7, so each CU's two resident blocks sum to a near-constant chain.
  const int g    = bid >> 5;
  const int qblk = (g < 8) ? (15 - g) : (g - 8);
  const int h    = bid & 7;
  const int b    = (bid >> 3) & 3;
  const int q0   = qblk * ROWS_BLK;

  const int tid  = (int)threadIdx.x;
  const int wave = tid >> 6;
  const int lane = tid & 63;
  const int quad = lane >> 4;
  const int col  = lane & 15;
  const int qw   = q0 + wave * 16;

  const size_t bhQ = (size_t)b * Lc * HD + (size_t)h * Dc;

  // ---- staging source pointers (per-lane, XOR swizzle folded into source) ----
  // K: load i covers keys i*64 + (tid>>3); 8 chunks of 16B per 128B row.
  const int kr = tid >> 3;
  const bf16_t* ksrc = Kb + bhQ + (size_t)kr * HD + (((tid & 7) ^ (kr & 7)) << 3);
  // V: load i covers d rows i*32 + wave*4 + (lane>>4); 256B rows, swizzle per half.
  const int vd  = wave * 4 + (lane >> 4);
  const int vhh = (lane >> 3) & 1;
  const int vc  = lane & 7;
  const bf16_t* vsrc = Vt + ((size_t)((b * Hc + h) * Dc + vd)) * Lc
                         + vhh * 64 + ((vc ^ (vd & 7)) << 3);
  const bf16_t* vsrc2 = vsrc + (size_t)32 * Lc;   // d rows +32 (same low-3 bits -> same swizzle)

  // ---- Q fragments (A-layout: row=col, k=quad*8+j) ----
  // prescale by 1/sqrt(64) * log2(e) so softmax uses exp2 directly
  bf16x8 aq[2];
  {
    const float* qp = Qg + bhQ + (size_t)(qw + col) * HD + quad * 8;
    const float SC = 0.125f * 1.44269504f;
#pragma unroll
    for (int t = 0; t < 2; ++t) {
      float4 lo = *(const float4*)(qp + t * 32);
      float4 hi = *(const float4*)(qp + t * 32 + 4);
      bf16x8 v;
      v[0] = (bf16_t)(lo.x * SC); v[1] = (bf16_t)(lo.y * SC);
      v[2] = (bf16_t)(lo.z * SC); v[3] = (bf16_t)(lo.w * SC);
      v[4] = (bf16_t)(hi.x * SC); v[5] = (bf16_t)(hi.y * SC);
      v[6] = (bf16_t)(hi.z * SC); v[7] = (bf16_t)(hi.w * SC);
      aq[t] = v;
    }
  }

  // ---- per-row mask parameters (C-layout rows: quad*4 + r) ----
  const bool testblk = (q0 >= TRAINc);
  int kend[4], cstart[4], qir[4];
#pragma unroll
  for (int r = 0; r < 4; ++r) {
    int qi = qw + quad * 4 + r;
    qir[r] = qi;
    if (testblk) {
      kend[r]   = ATT[b * 64 + ((qi - TRAINc) >> 3)] + 1;
      cstart[r] = qi & ~7;
    } else {
      kend[r]   = qi + 1;
      cstart[r] = 0;
    }
  }

  int ntA, ndiag, kfull_end;
  if (testblk) {
    int c0 = (q0 - TRAINc) >> 3;               // 16 chunks per 128-row block
    int amax = 0, amin = 0x7fffffff;
#pragma unroll
    for (int i = 0; i < 16; ++i) {
      int a = ATT[b * 64 + c0 + i];
      amax = (a > amax) ? a : amax;
      amin = (a < amin) ? a : amin;
    }
    ntA = (amax >> 7) + 1;   // 128-wide tiles covering [0, amax]; <= 12 (amax < 1536 <= q0)
    ndiag = 1;               // own 128-wide diagonal tile at k0=q0
    kfull_end = amin + 1;
  } else {
    ntA = qblk + 1;          // causal 128-wide tiles covering [0, q0+128)
    ndiag = 0;
    kfull_end = q0 + 1;
  }
  const int ntot = ntA + ndiag;

  float lsumL[4] = {0.f, 0.f, 0.f, 0.f};
  f32x4 o[4] = {{0,0,0,0},{0,0,0,0},{0,0,0,0},{0,0,0,0}};

  const int cA = ((quad ^ (col & 7)) << 3);   // swizzled 16B slot (within a 128B group)
  const int c7 = col & 7;
  const int c8 = col >> 3;

  // prologue: stage tile 0 into buf 0 (tile 0 always k0=0)
  {
    load16(ksrc,                      Klds[0] + wave * 512);
    load16(ksrc + (size_t)64 * HD,    Klds[0] + 4096 + wave * 512);
    load16(vsrc,                      Vlds[0] + wave * 512);
    load16(vsrc2,                     Vlds[0] + 4096 + wave * 512);
  }

  for (int ti = 0; ti < ntot; ++ti) {
    const int buf = ti & 1;
    __syncthreads();   // drains vmcnt -> buf[ti&1] ready; prior reads of other buf done

    if (ti + 1 < ntot) {   // prefetch next tile; stays in flight across compute
      const int kn = (ti + 1 < ntA) ? (ti + 1) * KT : q0;
      bf16_t* kd = Klds[1 - buf];
      bf16_t* vdl = Vlds[1 - buf];
      load16(ksrc + (size_t)kn * HD,        kd + wave * 512);
      load16(ksrc + (size_t)(kn + 64) * HD, kd + 4096 + wave * 512);
      load16(vsrc + kn,                     vdl + wave * 512);
      load16(vsrc2 + kn,                    vdl + 4096 + wave * 512);
    }

    const bf16_t* kb = Klds[buf];
    const bf16_t* vbuf = Vlds[buf];
    const int k0 = (ti < ntA) ? ti * KT : q0;

    // ---- S = Q K^T  (16 x 128: 8 key-groups) ----
    f32x4 sf[8] = {{0,0,0,0},{0,0,0,0},{0,0,0,0},{0,0,0,0},
                   {0,0,0,0},{0,0,0,0},{0,0,0,0},{0,0,0,0}};
    __builtin_amdgcn_s_setprio(1);
#pragma unroll
    for (int kg = 0; kg < 8; ++kg) {
      const bf16_t* krow = kb + (kg * 16 + col) * 64;
      bf16x8 k0f = *(const bf16x8*)(krow + cA);
      bf16x8 k1f = *(const bf16x8*)(krow + (cA ^ 32));
      sf[kg] = MFMA16(aq[0], k0f, sf[kg]);
      sf[kg] = MFMA16(aq[1], k1f, sf[kg]);
    }
    __builtin_amdgcn_s_setprio(0);

    const int mode = (ti >= ntA) ? 2 : ((k0 + KT <= kfull_end) ? 0 : 1);
    if (mode == 1) {
#pragma unroll
      for (int kg = 0; kg < 8; ++kg) {
        const int kgv = k0 + kg * 16 + col;
#pragma unroll
        for (int r = 0; r < 4; ++r)
          if (kgv >= kend[r]) sf[kg][r] = -1e30f;
      }
    } else if (mode == 2) {
#pragma unroll
      for (int kg = 0; kg < 8; ++kg) {
        const int kgv = k0 + kg * 16 + col;
#pragma unroll
        for (int r = 0; r < 4; ++r)
          if (kgv < cstart[r] || kgv > qir[r]) sf[kg][r] = -1e30f;
      }
    }

    // ---- two 64-key halves: exp2 -> P (per-wave LDS) -> PV ----
    // P row = 128B = 8 x 16B slots; logical slot s of row r stored at s^(r&7).
    bf16_t* pw = Plds[wave];
#pragma unroll
    for (int hh = 0; hh < 2; ++hh) {
#pragma unroll
      for (int kgl = 0; kgl < 4; ++kgl) {
#pragma unroll
        for (int r = 0; r < 4; ++r) {
          float p = __builtin_amdgcn_exp2f(sf[hh * 4 + kgl][r]);
          lsumL[r] += p;
          const int row = quad * 4 + r;
          pw[row * 64 + (((2 * kgl + c8) ^ (row & 7)) << 3) + c7] = (bf16_t)p;
        }
      }
      bf16x8 pa0 = *(const bf16x8*)&pw[col * 64 + ((quad ^ c7) << 3)];
      bf16x8 pa1 = *(const bf16x8*)&pw[col * 64 + (((4 + quad) ^ c7) << 3)];

      __builtin_amdgcn_s_setprio(1);
#pragma unroll
      for (int t = 0; t < 4; ++t) {
        const bf16_t* vrow = vbuf + (t * 16 + col) * 128 + hh * 64;
        bf16x8 v0 = *(const bf16x8*)(vrow + cA);
        bf16x8 v1 = *(const bf16x8*)(vrow + (cA ^ 32));
        o[t] = MFMA16(pa0, v0, o[t]);
        o[t] = MFMA16(pa1, v1, o[t]);
      }
      __builtin_amdgcn_s_setprio(0);
    }
  }

  // ---- epilogue: reduce lsum across the 16 cols, normalize, store ----
#pragma unroll
  for (int r = 0; r < 4; ++r) {
    float rs = lsumL[r];
    rs += __shfl_xor(rs, 1);
    rs += __shfl_xor(rs, 2);
    rs += __shfl_xor(rs, 4);
    rs += __shfl_xor(rs, 8);
    float inv = 1.f / rs;
    int qi = qw + quad * 4 + r;
    float* op = OUT + ((size_t)b * Lc + qi) * HD + (size_t)h * Dc + col;
    op[0]  = o[0][r] * inv;
    op[16] = o[1][r] * inv;
    op[32] = o[2][r] * inv;
    op[48] = o[3][r] * inv;
  }
}

extern "C" void kernel_launch(void* const* d_in, const int* in_sizes, int n_in,
                              void* d_out, int out_size, void* d_ws, size_t ws_size,
                              hipStream_t stream) {
  const float* Q   = (const float*)d_in[0];
  const float* K   = (const float*)d_in[1];
  const float* V   = (const float*)d_in[2];
  const int*   ATT = (const int*)d_in[3];
  float* OUT = (float*)d_out;
  (void)in_sizes; (void)n_in; (void)out_size; (void)ws_size;

  const size_t NE = (size_t)Bc * Lc * Hc * Dc;
  bf16_t* Kb = (bf16_t*)d_ws;
  bf16_t* Vt = Kb + NE;

  prep_fused<<<dim3((unsigned)(PREPK_BLOCKS + Bc * Hc * (Lc / 64))), dim3(256), 0, stream>>>(K, Kb, V, Vt);
  continual_attn<<<dim3(Bc * Hc * (Lc / ROWS_BLK)), dim3(512), 0, stream>>>(Q, Kb, Vt, ATT, OUT);
}

// Round 5
// 139.296 us; speedup vs baseline: 1.0095x; 1.0095x over previous
//
#include <hip/hip_runtime.h>
#include <hip/hip_bf16.h>

typedef __bf16 bf16_t;
typedef __bf16 bf16x8 __attribute__((ext_vector_type(8)));
typedef float  f32x4  __attribute__((ext_vector_type(4)));

#define MFMA16(a, b, c) __builtin_amdgcn_mfma_f32_16x16x32_bf16((a), (b), (c), 0, 0, 0)

constexpr int Bc = 4, Lc = 2048, Hc = 8, Dc = 64;
constexpr int HD = Hc * Dc;            // 512
constexpr int TRAINc = 1536;
constexpr int ROWS_BLK = 128;          // q rows per workgroup (4 waves x 32)
constexpr int KT = 64;                 // keys per k-tile

constexpr int PREPK_BLOCKS = (int)((size_t)Bc * Lc * Hc * Dc / 8 / 256);  // 2048

// ---------------- fused prep: K cast + V transpose in one launch ----------------
__global__ void prep_fused(const float* __restrict__ K, bf16_t* __restrict__ Kb,
                           const float* __restrict__ V, bf16_t* __restrict__ Vt) {
  // [64][64] tile; 8-elem (16B) chunk c of row r stored at chunk c ^ (r>>3):
  // column reads then spread 64 lanes over all 32 banks (2/bank = free).
  __shared__ bf16_t T[64][64];
  const int t = (int)threadIdx.x;

  if ((int)blockIdx.x < PREPK_BLOCKS) {
    size_t g = ((size_t)blockIdx.x * 256 + t) * 8;
    float4 a = *(const float4*)(K + g);
    float4 b = *(const float4*)(K + g + 4);
    bf16x8 v;
    v[0] = (bf16_t)a.x; v[1] = (bf16_t)a.y; v[2] = (bf16_t)a.z; v[3] = (bf16_t)a.w;
    v[4] = (bf16_t)b.x; v[5] = (bf16_t)b.y; v[6] = (bf16_t)b.z; v[7] = (bf16_t)b.w;
    *(bf16x8*)(Kb + g) = v;
    return;
  }

  const int bid = (int)blockIdx.x - PREPK_BLOCKS;
  const int kt = bid & 31, h = (bid >> 5) & 7, b = bid >> 8;
  {
    int kl = t >> 2, dp = (t & 3) << 4;
    const float* s = V + ((size_t)(b * Lc + kt * 64 + kl) * Hc + h) * Dc + dp;
    bf16x8 v0, v1;
    float4 f;
    f = *(const float4*)(s);      v0[0]=(bf16_t)f.x; v0[1]=(bf16_t)f.y; v0[2]=(bf16_t)f.z; v0[3]=(bf16_t)f.w;
    f = *(const float4*)(s + 4);  v0[4]=(bf16_t)f.x; v0[5]=(bf16_t)f.y; v0[6]=(bf16_t)f.z; v0[7]=(bf16_t)f.w;
    f = *(const float4*)(s + 8);  v1[0]=(bf16_t)f.x; v1[1]=(bf16_t)f.y; v1[2]=(bf16_t)f.z; v1[3]=(bf16_t)f.w;
    f = *(const float4*)(s + 12); v1[4]=(bf16_t)f.x; v1[5]=(bf16_t)f.y; v1[6]=(bf16_t)f.z; v1[7]=(bf16_t)f.w;
    const int x = kl >> 3;
    const int c0 = dp >> 3;
    *(bf16x8*)&T[kl][(c0 ^ x) << 3]       = v0;
    *(bf16x8*)&T[kl][((c0 + 1) ^ x) << 3] = v1;
  }
  __syncthreads();
  {
    int d = t >> 2, kp = (t & 3) << 4;
    const int xa = kp >> 3;
    const int xb = xa + 1;
    const int lo = d & 7, hi = d >> 3;
    const int x0 = ((hi ^ xa) << 3) + lo;
    const int x1 = ((hi ^ xb) << 3) + lo;
    bf16x8 o0, o1;
#pragma unroll
    for (int i = 0; i < 8; ++i) { o0[i] = T[kp + i][x0]; o1[i] = T[kp + 8 + i][x1]; }
    bf16_t* dst = Vt + ((size_t)((b * Hc + h) * Dc + d)) * Lc + kt * 64 + kp;
    *(bf16x8*)dst = o0;
    *(bf16x8*)(dst + 8) = o1;
  }
}

// ---------------- main attention ----------------
static __device__ __forceinline__ void load16(const bf16_t* g, bf16_t* l) {
  __builtin_amdgcn_global_load_lds(
      (const __attribute__((address_space(1))) unsigned int*)g,
      (__attribute__((address_space(3))) unsigned int*)l, 16, 0, 0);
}

// 4 waves x 32 q-rows = 128 q-rows per block. Each wave owns TWO 16-row
// fragments: K/V LDS fragments are read ONCE and feed both fragments' MFMAs,
// halving the LDS read traffic per q-row (the measured bottleneck).
__global__ __launch_bounds__(256, 2)
void continual_attn(const float* __restrict__ Qg, const bf16_t* __restrict__ Kb,
                    const bf16_t* __restrict__ Vt, const int* __restrict__ ATT,
                    float* __restrict__ OUT)
{
  // [key][64] / [d][64] rows of 128B; 16B slot s of row r holds logical chunk s^(r&7)
  __shared__ __align__(16) bf16_t Klds[2][KT * 64];   // 2 x 8 KB
  __shared__ __align__(16) bf16_t Vlds[2][Dc * KT];   // 2 x 8 KB
  __shared__ __align__(16) bf16_t Plds[4][32 * 64];   // 16 KB  (total 48 KB -> 2 blk/CU)

  const int bid  = blockIdx.x;
  // complementary pairing: first 256 blocks get qblk 15..8 (heavy), second 256
  // get 0..7, so each CU's two resident blocks sum to a near-constant chain.
  const int gg   = bid >> 5;
  const int qblk = (gg < 8) ? (15 - gg) : (gg - 8);
  const int h    = bid & 7;
  const int b    = (bid >> 3) & 3;
  const int q0   = qblk * ROWS_BLK;

  const int tid  = (int)threadIdx.x;
  const int wave = tid >> 6;
  const int lane = tid & 63;
  const int quad = lane >> 4;
  const int col  = lane & 15;
  const int qw0  = q0 + wave * 32;     // this wave's 32-row range

  const size_t bhQ = (size_t)b * Lc * HD + (size_t)h * Dc;

  // staging source pointers (256 threads cover 32 rows/call; XOR swizzle on source)
  const int kr = tid >> 3;                                   // row 0..31
  const int sw = ((tid & 7) ^ (kr & 7)) << 3;
  const bf16_t* ksrcA = Kb + bhQ + (size_t)kr * HD + sw;
  const bf16_t* vsrcA = Vt + ((size_t)((b * Hc + h) * Dc + kr)) * Lc + sw;
  const bf16_t* vsrcB = vsrcA + (size_t)32 * Lc;             // d rows 32..63

  // ---- Q fragments, two 16-row groups (A-layout: row=col, k=quad*8+j) ----
  // prescale by 1/sqrt(64) * log2(e) so softmax uses exp2 directly
  bf16x8 aq[2][2];
#pragma unroll
  for (int g = 0; g < 2; ++g) {
    const float* qp = Qg + bhQ + (size_t)(qw0 + g * 16 + col) * HD + quad * 8;
    const float SC = 0.125f * 1.44269504f;
#pragma unroll
    for (int t = 0; t < 2; ++t) {
      float4 lo = *(const float4*)(qp + t * 32);
      float4 hi = *(const float4*)(qp + t * 32 + 4);
      bf16x8 v;
      v[0] = (bf16_t)(lo.x * SC); v[1] = (bf16_t)(lo.y * SC);
      v[2] = (bf16_t)(lo.z * SC); v[3] = (bf16_t)(lo.w * SC);
      v[4] = (bf16_t)(hi.x * SC); v[5] = (bf16_t)(hi.y * SC);
      v[6] = (bf16_t)(hi.z * SC); v[7] = (bf16_t)(hi.w * SC);
      aq[g][t] = v;
    }
  }

  // ---- per-row mask parameters (C-layout rows: g*16 + quad*4 + r) ----
  const bool testblk = (q0 >= TRAINc);
  int kend[2][4], qir[2][4];
#pragma unroll
  for (int g = 0; g < 2; ++g)
#pragma unroll
    for (int r = 0; r < 4; ++r) {
      int qi = qw0 + g * 16 + quad * 4 + r;
      qir[g][r] = qi;
      kend[g][r] = testblk ? (ATT[b * 64 + ((qi - TRAINc) >> 3)] + 1) : (qi + 1);
    }

  int ntA, ndiag, kfull_end;
  if (testblk) {
    int c0 = (q0 - TRAINc) >> 3;               // 16 chunks per 128-row block
    int amax = 0, amin = 0x7fffffff;
#pragma unroll
    for (int i = 0; i < 16; ++i) {
      int a = ATT[b * 64 + c0 + i];
      amax = (a > amax) ? a : amax;
      amin = (a < amin) ? a : amin;
    }
    ntA = (amax >> 6) + 1;   // 64-wide tiles covering [0, amax]
    ndiag = 2;               // own 128-wide diagonal region at k0=q0
    kfull_end = amin + 1;
  } else {
    ntA = 2 * qblk + 2;      // causal tiles covering [0, q0+128)
    ndiag = 0;
    kfull_end = q0 + 1;
  }
  const int ntot = ntA + ndiag;

  float lsumL[2][4] = {{0.f,0.f,0.f,0.f},{0.f,0.f,0.f,0.f}};
  f32x4 o[2][4] = {{{0,0,0,0},{0,0,0,0},{0,0,0,0},{0,0,0,0}},
                   {{0,0,0,0},{0,0,0,0},{0,0,0,0},{0,0,0,0}}};

  const int cA = ((quad ^ (col & 7)) << 3);   // swizzled 16B slot for k/d 0..31
  const int c7 = col & 7;
  const int c8 = col >> 3;

  // prologue: stage tile 0 into buf 0 (tile 0 always k0=0)
  {
    load16(ksrcA,                    Klds[0] + wave * 512);
    load16(ksrcA + (size_t)32 * HD,  Klds[0] + 2048 + wave * 512);
    load16(vsrcA,                    Vlds[0] + wave * 512);
    load16(vsrcB,                    Vlds[0] + 2048 + wave * 512);
  }

  for (int ti = 0; ti < ntot; ++ti) {
    const int buf = ti & 1;
    __syncthreads();   // drains vmcnt -> buf[ti&1] ready; prior reads of other buf done

    if (ti + 1 < ntot) {   // prefetch next tile; stays in flight across compute
      const int kn = (ti + 1 < ntA) ? (ti + 1) * KT : q0 + (ti + 1 - ntA) * KT;
      bf16_t* kd = Klds[1 - buf];
      bf16_t* vd = Vlds[1 - buf];
      load16(ksrcA + (size_t)kn * HD,        kd + wave * 512);
      load16(ksrcA + (size_t)(kn + 32) * HD, kd + 2048 + wave * 512);
      load16(vsrcA + kn,                     vd + wave * 512);
      load16(vsrcB + kn,                     vd + 2048 + wave * 512);
    }

    const bf16_t* kb = Klds[buf];
    const bf16_t* vbuf = Vlds[buf];
    const int k0 = (ti < ntA) ? ti * KT : q0 + (ti - ntA) * KT;

    // ---- S = Q K^T (32 x 64): K fragments read once, used by both q-groups ----
    f32x4 sf[2][4] = {{{0,0,0,0},{0,0,0,0},{0,0,0,0},{0,0,0,0}},
                      {{0,0,0,0},{0,0,0,0},{0,0,0,0},{0,0,0,0}}};
    __builtin_amdgcn_s_setprio(1);
#pragma unroll
    for (int kg = 0; kg < 4; ++kg) {
      const bf16_t* krow = kb + (kg * 16 + col) * 64;
      bf16x8 k0f = *(const bf16x8*)(krow + cA);
      bf16x8 k1f = *(const bf16x8*)(krow + (cA ^ 32));
#pragma unroll
      for (int g = 0; g < 2; ++g) {
        sf[g][kg] = MFMA16(aq[g][0], k0f, sf[g][kg]);
        sf[g][kg] = MFMA16(aq[g][1], k1f, sf[g][kg]);
      }
    }
    __builtin_amdgcn_s_setprio(0);

    const int mode = (ti >= ntA) ? 2 : ((k0 + KT <= kfull_end) ? 0 : 1);
    if (mode == 1) {
#pragma unroll
      for (int kg = 0; kg < 4; ++kg) {
        const int kgv = k0 + kg * 16 + col;
#pragma unroll
        for (int g = 0; g < 2; ++g)
#pragma unroll
          for (int r = 0; r < 4; ++r)
            if (kgv >= kend[g][r]) sf[g][kg][r] = -1e30f;
      }
    } else if (mode == 2) {
#pragma unroll
      for (int kg = 0; kg < 4; ++kg) {
        const int kgv = k0 + kg * 16 + col;
#pragma unroll
        for (int g = 0; g < 2; ++g)
#pragma unroll
          for (int r = 0; r < 4; ++r)
            if (kgv < (qir[g][r] & ~7) || kgv > qir[g][r]) sf[g][kg][r] = -1e30f;
      }
    }

    // ---- exp2 (fixed-max: logits*log2e bounded ~8, exp2 <= ~250, fp32/bf16-safe) ----
    // P rows 0..31 (g*16 + quad*4 + r); row = 128B = 8 slots, slot s at s^(row&7)
    bf16_t* pw = Plds[wave];
#pragma unroll
    for (int g = 0; g < 2; ++g)
#pragma unroll
      for (int kg = 0; kg < 4; ++kg)
#pragma unroll
        for (int r = 0; r < 4; ++r) {
          float p = __builtin_amdgcn_exp2f(sf[g][kg][r]);
          lsumL[g][r] += p;
          const int row = g * 16 + quad * 4 + r;
          pw[row * 64 + (((2 * kg + c8) ^ (row & 7)) << 3) + c7] = (bf16_t)p;
        }

    bf16x8 pa0[2], pa1[2];
#pragma unroll
    for (int g = 0; g < 2; ++g) {
      pa0[g] = *(const bf16x8*)&pw[(g * 16 + col) * 64 + ((quad ^ c7) << 3)];
      pa1[g] = *(const bf16x8*)&pw[(g * 16 + col) * 64 + (((4 + quad) ^ c7) << 3)];
    }

    // ---- O += P V: V fragments read once, used by both q-groups ----
    __builtin_amdgcn_s_setprio(1);
#pragma unroll
    for (int t = 0; t < 4; ++t) {
      const bf16_t* vrow = vbuf + (t * 16 + col) * 64;
      bf16x8 v0 = *(const bf16x8*)(vrow + cA);
      bf16x8 v1 = *(const bf16x8*)(vrow + (cA ^ 32));
#pragma unroll
      for (int g = 0; g < 2; ++g) {
        o[g][t] = MFMA16(pa0[g], v0, o[g][t]);
        o[g][t] = MFMA16(pa1[g], v1, o[g][t]);
      }
    }
    __builtin_amdgcn_s_setprio(0);
  }

  // ---- epilogue: reduce lsum across the 16 cols, normalize, store ----
#pragma unroll
  for (int g = 0; g < 2; ++g)
#pragma unroll
    for (int r = 0; r < 4; ++r) {
      float rs = lsumL[g][r];
      rs += __shfl_xor(rs, 1);
      rs += __shfl_xor(rs, 2);
      rs += __shfl_xor(rs, 4);
      rs += __shfl_xor(rs, 8);
      float inv = 1.f / rs;
      int qi = qw0 + g * 16 + quad * 4 + r;
      float* op = OUT + ((size_t)b * Lc + qi) * HD + (size_t)h * Dc + col;
      op[0]  = o[g][0][r] * inv;
      op[16] = o[g][1][r] * inv;
      op[32] = o[g][2][r] * inv;
      op[48] = o[g][3][r] * inv;
    }
}

extern "C" void kernel_launch(void* const* d_in, const int* in_sizes, int n_in,
                              void* d_out, int out_size, void* d_ws, size_t ws_size,
                              hipStream_t stream) {
  const float* Q   = (const float*)d_in[0];
  const float* K   = (const float*)d_in[1];
  const float* V   = (const float*)d_in[2];
  const int*   ATT = (const int*)d_in[3];
  float* OUT = (float*)d_out;
  (void)in_sizes; (void)n_in; (void)out_size; (void)ws_size;

  const size_t NE = (size_t)Bc * Lc * Hc * Dc;
  bf16_t* Kb = (bf16_t*)d_ws;
  bf16_t* Vt = Kb + NE;

  prep_fused<<<dim3((unsigned)(PREPK_BLOCKS + Bc * Hc * (Lc / 64))), dim3(256), 0, stream>>>(K, Kb, V, Vt);
  continual_attn<<<dim3(Bc * Hc * (Lc / ROWS_BLK)), dim3(256), 0, stream>>>(Q, Kb, Vt, ATT, OUT);
}

// Round 6
// 126.671 us; speedup vs baseline: 1.1101x; 1.0997x over previous
//
#include <hip/hip_runtime.h>
#include <hip/hip_bf16.h>

typedef __bf16 bf16_t;
typedef __bf16 bf16x8 __attribute__((ext_vector_type(8)));
typedef float  f32x4  __attribute__((ext_vector_type(4)));

#define MFMA16(a, b, c) __builtin_amdgcn_mfma_f32_16x16x32_bf16((a), (b), (c), 0, 0, 0)

constexpr int Bc = 4, Lc = 2048, Hc = 8, Dc = 64;
constexpr int HD = Hc * Dc;            // 512
constexpr int TRAINc = 1536;
constexpr int ROWS_BLK = 64;           // q rows per workgroup (4 waves x 16)
constexpr int KT = 64;                 // keys per k-tile

constexpr int PREPK_BLOCKS = (int)((size_t)Bc * Lc * Hc * Dc / 8 / 256);  // 2048

// ---------------- fused prep: K cast + V transpose in one launch ----------------
__global__ void prep_fused(const float* __restrict__ K, bf16_t* __restrict__ Kb,
                           const float* __restrict__ V, bf16_t* __restrict__ Vt) {
  // [64][64] tile; 8-elem (16B) chunk c of row r stored at chunk c ^ (r>>3):
  // column reads then spread 64 lanes over all 32 banks (2/bank = free).
  __shared__ bf16_t T[64][64];
  const int t = (int)threadIdx.x;

  if ((int)blockIdx.x < PREPK_BLOCKS) {
    size_t g = ((size_t)blockIdx.x * 256 + t) * 8;
    float4 a = *(const float4*)(K + g);
    float4 b = *(const float4*)(K + g + 4);
    bf16x8 v;
    v[0] = (bf16_t)a.x; v[1] = (bf16_t)a.y; v[2] = (bf16_t)a.z; v[3] = (bf16_t)a.w;
    v[4] = (bf16_t)b.x; v[5] = (bf16_t)b.y; v[6] = (bf16_t)b.z; v[7] = (bf16_t)b.w;
    *(bf16x8*)(Kb + g) = v;
    return;
  }

  const int bid = (int)blockIdx.x - PREPK_BLOCKS;
  const int kt = bid & 31, h = (bid >> 5) & 7, b = bid >> 8;
  {
    int kl = t >> 2, dp = (t & 3) << 4;
    const float* s = V + ((size_t)(b * Lc + kt * 64 + kl) * Hc + h) * Dc + dp;
    bf16x8 v0, v1;
    float4 f;
    f = *(const float4*)(s);      v0[0]=(bf16_t)f.x; v0[1]=(bf16_t)f.y; v0[2]=(bf16_t)f.z; v0[3]=(bf16_t)f.w;
    f = *(const float4*)(s + 4);  v0[4]=(bf16_t)f.x; v0[5]=(bf16_t)f.y; v0[6]=(bf16_t)f.z; v0[7]=(bf16_t)f.w;
    f = *(const float4*)(s + 8);  v1[0]=(bf16_t)f.x; v1[1]=(bf16_t)f.y; v1[2]=(bf16_t)f.z; v1[3]=(bf16_t)f.w;
    f = *(const float4*)(s + 12); v1[4]=(bf16_t)f.x; v1[5]=(bf16_t)f.y; v1[6]=(bf16_t)f.z; v1[7]=(bf16_t)f.w;
    const int x = kl >> 3;
    const int c0 = dp >> 3;
    *(bf16x8*)&T[kl][(c0 ^ x) << 3]       = v0;
    *(bf16x8*)&T[kl][((c0 + 1) ^ x) << 3] = v1;
  }
  __syncthreads();
  {
    int d = t >> 2, kp = (t & 3) << 4;
    const int xa = kp >> 3;
    const int xb = xa + 1;
    const int lo = d & 7, hi = d >> 3;
    const int x0 = ((hi ^ xa) << 3) + lo;
    const int x1 = ((hi ^ xb) << 3) + lo;
    bf16x8 o0, o1;
#pragma unroll
    for (int i = 0; i < 8; ++i) { o0[i] = T[kp + i][x0]; o1[i] = T[kp + 8 + i][x1]; }
    bf16_t* dst = Vt + ((size_t)((b * Hc + h) * Dc + d)) * Lc + kt * 64 + kp;
    *(bf16x8*)dst = o0;
    *(bf16x8*)(dst + 8) = o1;
  }
}

// ---------------- main attention ----------------
static __device__ __forceinline__ void load16(const bf16_t* g, bf16_t* l) {
  __builtin_amdgcn_global_load_lds(
      (const __attribute__((address_space(1))) unsigned int*)g,
      (__attribute__((address_space(3))) unsigned int*)l, 16, 0, 0);
}

static __device__ __forceinline__ bf16x8 mk8(unsigned w0, unsigned w1,
                                             unsigned w2, unsigned w3) {
  union { unsigned u[4]; bf16x8 v; } x;
  x.u[0] = w0; x.u[1] = w1; x.u[2] = w2; x.u[3] = w3;
  return x.v;
}

// Swapped-QK^T softmax (T12 adapted to 16x16): compute S^T = mfma(K, Q) so each
// lane holds a full 16-key P slice for ONE q-row (q = col). P goes to bf16 via
// v_cvt_pk_bf16_f32 and is redistributed across quads with permlane16/32_swap
// to form the PV A-fragments IN REGISTER -- no P LDS round-trip at all.
__global__ __launch_bounds__(256, 4)
void continual_attn(const float* __restrict__ Qg, const bf16_t* __restrict__ Kb,
                    const bf16_t* __restrict__ Vt, const int* __restrict__ ATT,
                    float* __restrict__ OUT)
{
  // [key][64] / [d][64] rows of 128B; 16B slot s of row r holds logical chunk s^(r&7)
  __shared__ __align__(16) bf16_t Klds[2][KT * 64];   // 2 x 8 KB
  __shared__ __align__(16) bf16_t Vlds[2][Dc * KT];   // 2 x 8 KB  (total 32 KB)

  const int bid  = blockIdx.x;
  const int qblk = 31 - (bid >> 5);   // heavy q-blocks dispatch first
  const int h    = bid & 7;
  const int b    = (bid >> 3) & 3;
  const int q0   = qblk * ROWS_BLK;

  const int tid  = (int)threadIdx.x;
  const int wave = tid >> 6;
  const int lane = tid & 63;
  const int quad = lane >> 4;
  const int col  = lane & 15;
  const int qw   = q0 + wave * 16;

  const size_t bhQ = (size_t)b * Lc * HD + (size_t)h * Dc;

  // staging source pointers (per-lane; k-offset added per tile). XOR swizzle on source.
  const int kr = tid >> 3;                                   // row 0..31
  const bf16_t* ksrcA = Kb + bhQ + (size_t)kr * HD + (((tid & 7) ^ (kr & 7)) << 3);
  const bf16_t* vsrcA = Vt + ((size_t)((b * Hc + h) * Dc + kr)) * Lc + (((tid & 7) ^ (kr & 7)) << 3);
  const bf16_t* vsrcB = vsrcA + (size_t)32 * Lc;             // d rows 32..63, same swizzle

  // ---- Q fragments (row=col, k=quad*8+j), prescaled by 1/8 * log2(e) ----
  bf16x8 aq[2];
  {
    const float* qp = Qg + bhQ + (size_t)(qw + col) * HD + quad * 8;
    const float SC = 0.125f * 1.44269504f;
#pragma unroll
    for (int t = 0; t < 2; ++t) {
      float4 lo = *(const float4*)(qp + t * 32);
      float4 hi = *(const float4*)(qp + t * 32 + 4);
      bf16x8 v;
      v[0] = (bf16_t)(lo.x * SC); v[1] = (bf16_t)(lo.y * SC);
      v[2] = (bf16_t)(lo.z * SC); v[3] = (bf16_t)(lo.w * SC);
      v[4] = (bf16_t)(hi.x * SC); v[5] = (bf16_t)(hi.y * SC);
      v[6] = (bf16_t)(hi.z * SC); v[7] = (bf16_t)(hi.w * SC);
      aq[t] = v;
    }
  }

  // ---- per-lane mask scalars (this lane's q-row is q = qw + col) ----
  const bool testblk = (q0 >= TRAINc);
  const int qi = qw + col;
  int kendL, cstartL;
  if (testblk) {
    kendL   = ATT[b * 64 + ((qi - TRAINc) >> 3)] + 1;
    cstartL = qi & ~7;
  } else {
    kendL   = qi + 1;
    cstartL = 0;
  }

  int ntA, ndiag, kfull_end;
  if (testblk) {
    int c0 = (q0 - TRAINc) >> 3;
    int amax = 0, amin = 0x7fffffff;
#pragma unroll
    for (int i = 0; i < 8; ++i) {
      int a = ATT[b * 64 + c0 + i];
      amax = (a > amax) ? a : amax;
      amin = (a < amin) ? a : amin;
    }
    ntA = (amax >> 6) + 1;   // 64-wide tiles covering [0, amax]
    ndiag = 1;               // own 64-wide diagonal block at k0=q0
    kfull_end = amin + 1;
  } else {
    ntA = qblk + 1;          // causal tiles covering [0, q0+64)
    ndiag = 0;
    kfull_end = q0 + 1;
  }
  const int ntot = ntA + ndiag;

  float ls[4] = {0.f, 0.f, 0.f, 0.f};   // ILP partials; all belong to q = qw+col
  f32x4 o[4] = {{0,0,0,0},{0,0,0,0},{0,0,0,0},{0,0,0,0}};

  const int cA = ((quad ^ (col & 7)) << 3);   // swizzled 16B slot for k/d 0..31

  // prologue: stage tile 0 into buf 0 (tile 0 always k0=0)
  {
    bf16_t* kd = Klds[0];
    bf16_t* vd = Vlds[0];
    load16(ksrcA, kd + wave * 512);
    load16(ksrcA + (size_t)32 * HD, kd + 2048 + wave * 512);
    load16(vsrcA, vd + wave * 512);
    load16(vsrcB, vd + 2048 + wave * 512);
  }

  for (int ti = 0; ti < ntot; ++ti) {
    const int buf = ti & 1;
    __syncthreads();   // drains vmcnt -> buf[ti&1] ready; prior reads of other buf done

    if (ti + 1 < ntot) {   // prefetch next tile; stays in flight across compute
      const int kn = (ti + 1 < ntA) ? (ti + 1) * KT : q0 + (ti + 1 - ntA) * KT;
      bf16_t* kd = Klds[1 - buf];
      bf16_t* vd = Vlds[1 - buf];
      load16(ksrcA + (size_t)kn * HD, kd + wave * 512);
      load16(ksrcA + (size_t)(kn + 32) * HD, kd + 2048 + wave * 512);
      load16(vsrcA + kn, vd + wave * 512);
      load16(vsrcB + kn, vd + 2048 + wave * 512);
    }

    const bf16_t* kb = Klds[buf];
    const bf16_t* vbuf = Vlds[buf];
    const int k0 = (ti < ntA) ? ti * KT : q0 + (ti - ntA) * KT;

    // ---- S^T = K Q^T  (swapped operands; sf[kg][r] = S[key=k0+kg*16+quad*4+r][q=qi]) ----
    f32x4 sf[4] = {{0,0,0,0},{0,0,0,0},{0,0,0,0},{0,0,0,0}};
    __builtin_amdgcn_s_setprio(1);
#pragma unroll
    for (int kg = 0; kg < 4; ++kg) {
      const bf16_t* krow = kb + (kg * 16 + col) * 64;
      bf16x8 k0f = *(const bf16x8*)(krow + cA);
      bf16x8 k1f = *(const bf16x8*)(krow + (cA ^ 32));
      sf[kg] = MFMA16(k0f, aq[0], sf[kg]);
      sf[kg] = MFMA16(k1f, aq[1], sf[kg]);
    }
    __builtin_amdgcn_s_setprio(0);

    const int mode = (ti >= ntA) ? 2 : ((k0 + KT <= kfull_end) ? 0 : 1);
    if (mode == 1) {
#pragma unroll
      for (int kg = 0; kg < 4; ++kg) {
        const int kv = k0 + kg * 16 + quad * 4;
#pragma unroll
        for (int r = 0; r < 4; ++r)
          if (kv + r >= kendL) sf[kg][r] = -1e30f;
      }
    } else if (mode == 2) {
#pragma unroll
      for (int kg = 0; kg < 4; ++kg) {
        const int kv = k0 + kg * 16 + quad * 4;
#pragma unroll
        for (int r = 0; r < 4; ++r)
          if (kv + r < cstartL || kv + r > qi) sf[kg][r] = -1e30f;
      }
    }

    // ---- exp2 (fixed-max: logits*log2e bounded, exp2 fp32/bf16-safe) ----
    float pvv[4][4];
#pragma unroll
    for (int kg = 0; kg < 4; ++kg)
#pragma unroll
      for (int r = 0; r < 4; ++r) {
        float p = __builtin_amdgcn_exp2f(sf[kg][r]);
        pvv[kg][r] = p;
        ls[r] += p;
      }

    // ---- pack to bf16 pairs: Dw[kg][d] = (key 16kg+4quad+2d, +2d+1) for q=col ----
    unsigned Dw[4][2];
#pragma unroll
    for (int kg = 0; kg < 4; ++kg)
#pragma unroll
      for (int d = 0; d < 2; ++d)
        asm("v_cvt_pk_bf16_f32 %0, %1, %2"
            : "=v"(Dw[kg][d]) : "v"(pvv[kg][2 * d]), "v"(pvv[kg][2 * d + 1]));

    // ---- quad redistribution: (a,b) -> swap32 -> swap16 gives
    //      a = [a@q0|a@q2|b@q0|b@q2], b = [a@q1|a@q3|b@q1|b@q3]  (by quad) ----
    unsigned a0 = Dw[0][0], b0 = Dw[1][0];
    asm volatile("v_permlane32_swap_b32 %0, %1" : "+v"(a0), "+v"(b0));
    asm volatile("v_permlane16_swap_b32 %0, %1" : "+v"(a0), "+v"(b0));
    unsigned a1 = Dw[0][1], b1 = Dw[1][1];
    asm volatile("v_permlane32_swap_b32 %0, %1" : "+v"(a1), "+v"(b1));
    asm volatile("v_permlane16_swap_b32 %0, %1" : "+v"(a1), "+v"(b1));
    unsigned a2 = Dw[2][0], b2 = Dw[3][0];
    asm volatile("v_permlane32_swap_b32 %0, %1" : "+v"(a2), "+v"(b2));
    asm volatile("v_permlane16_swap_b32 %0, %1" : "+v"(a2), "+v"(b2));
    unsigned a3 = Dw[2][1], b3 = Dw[3][1];
    asm volatile("v_permlane32_swap_b32 %0, %1" : "+v"(a3), "+v"(b3));
    asm volatile("v_permlane16_swap_b32 %0, %1" : "+v"(a3), "+v"(b3));

    // pa0 holds P[q=col][keys quad*8+0..7], pa1 the same for keys 32..63
    bf16x8 pa0 = mk8(a0, a1, b0, b1);
    bf16x8 pa1 = mk8(a2, a3, b2, b3);

    // ---- O += P V  (4 d-tiles x 2 k-chunks) ----
    __builtin_amdgcn_s_setprio(1);
#pragma unroll
    for (int t = 0; t < 4; ++t) {
      const bf16_t* vrow = vbuf + (t * 16 + col) * 64;
      bf16x8 v0 = *(const bf16x8*)(vrow + cA);
      bf16x8 v1 = *(const bf16x8*)(vrow + (cA ^ 32));
      o[t] = MFMA16(pa0, v0, o[t]);
      o[t] = MFMA16(pa1, v1, o[t]);
    }
    __builtin_amdgcn_s_setprio(0);
  }

  // ---- epilogue: denom for q=qw+col lives per-lane; reduce over quads,
  //      then fetch per-output-row denominators with shfl, normalize, store ----
  float rs = (ls[0] + ls[1]) + (ls[2] + ls[3]);
  rs += __shfl_xor(rs, 16);
  rs += __shfl_xor(rs, 32);
#pragma unroll
  for (int r = 0; r < 4; ++r) {
    float dr = __shfl(rs, quad * 4 + r);   // lane (quad*4+r) has denom for q=qw+quad*4+r
    float inv = 1.f / dr;
    int qo = qw + quad * 4 + r;
    float* op = OUT + ((size_t)b * Lc + qo) * HD + (size_t)h * Dc + col;
    op[0]  = o[0][r] * inv;
    op[16] = o[1][r] * inv;
    op[32] = o[2][r] * inv;
    op[48] = o[3][r] * inv;
  }
}

extern "C" void kernel_launch(void* const* d_in, const int* in_sizes, int n_in,
                              void* d_out, int out_size, void* d_ws, size_t ws_size,
                              hipStream_t stream) {
  const float* Q   = (const float*)d_in[0];
  const float* K   = (const float*)d_in[1];
  const float* V   = (const float*)d_in[2];
  const int*   ATT = (const int*)d_in[3];
  float* OUT = (float*)d_out;
  (void)in_sizes; (void)n_in; (void)out_size; (void)ws_size;

  const size_t NE = (size_t)Bc * Lc * Hc * Dc;
  bf16_t* Kb = (bf16_t*)d_ws;
  bf16_t* Vt = Kb + NE;

  prep_fused<<<dim3((unsigned)(PREPK_BLOCKS + Bc * Hc * (Lc / 64))), dim3(256), 0, stream>>>(K, Kb, V, Vt);
  continual_attn<<<dim3(Bc * Hc * (Lc / ROWS_BLK)), dim3(256), 0, stream>>>(Q, Kb, Vt, ATT, OUT);
}